// Round 9
// baseline (227.330 us; speedup 1.0000x reference)
//
#include <hip/hip_runtime.h>
#include <hip/hip_bf16.h>
#include <math.h>

#define SEQ 4096
#define EMB 1024
#define NH  16
#define DK  64

typedef __attribute__((ext_vector_type(8))) unsigned short us8;
typedef __attribute__((ext_vector_type(8))) short         s8;
typedef __attribute__((ext_vector_type(4))) unsigned short us4;
typedef __attribute__((ext_vector_type(4))) float          f4;

static __device__ __forceinline__ unsigned short f2bf(float f) {
    union { float f; unsigned u; } v; v.f = f;
    unsigned r = v.u + 0x7FFF + ((v.u >> 16) & 1);
    return (unsigned short)(r >> 16);
}

__device__ __forceinline__ void gl2lds16(const void* g, void* l) {
    __builtin_amdgcn_global_load_lds((const __attribute__((address_space(1))) void*)g,
                                     (__attribute__((address_space(3))) void*)l, 16, 0, 0);
}

// pack two fp32 -> one dword of two truncated bf16 (hi = a, lo = b): one v_perm_b32
__device__ __forceinline__ int pkbf(float a, float b) {
    return (int)__builtin_amdgcn_perm(__float_as_uint(a), __float_as_uint(b), 0x07060302u);
}

// ---------------- fp32 -> bf16 convert, all 5 tensors in one launch ----------------
__global__ void cvt_all(const float* __restrict__ x,
                        const float* __restrict__ w0, const float* __restrict__ w1,
                        const float* __restrict__ w2, const float* __restrict__ w3,
                        unsigned short* __restrict__ xo,
                        unsigned short* __restrict__ o0, unsigned short* __restrict__ o1,
                        unsigned short* __restrict__ o2, unsigned short* __restrict__ o3) {
    const int idx = blockIdx.x * 256 + threadIdx.x;
    const float* in;
    unsigned short* out;
    int off;
    if (idx < (1 << 20)) { in = x; out = xo; off = idx; }
    else {
        const int t = idx - (1 << 20);
        const int w = t >> 18;
        off = t & ((1 << 18) - 1);
        in  = w == 0 ? w0 : (w == 1 ? w1 : (w == 2 ? w2 : w3));
        out = w == 0 ? o0 : (w == 1 ? o1 : (w == 2 ? o2 : o3));
    }
    const float4 v = ((const float4*)in)[off];
    us4 o;
    o[0] = f2bf(v.x); o[1] = f2bf(v.y); o[2] = f2bf(v.z); o[3] = f2bf(v.w);
    ((us4*)out)[off] = o;
}

// ---------------- bf16 64x64 transpose with k-permuted output columns ----------------
// pos(k): k=a*16+b*4+c -> (a>>1)*32 + b*8 + (a&1)*4 + c  (matches attn PV frag layout)
__global__ __launch_bounds__(256) void transpose_kernel(
    const unsigned short* __restrict__ in, unsigned short* __restrict__ out) {
    __shared__ unsigned short t[64][72];
    const int tid = threadIdx.x;
    const int row = tid >> 2, c = (tid & 3) * 16;
    const int gr = blockIdx.x * 64, gc = blockIdx.y * 64;
    const unsigned short* src = in + (size_t)(gr + row) * EMB + gc + c;
    *(us8*)&t[row][c]     = *(const us8*)src;
    *(us8*)&t[row][c + 8] = *(const us8*)(src + 8);
    __syncthreads();
    us8 o0, o1;
#pragma unroll
    for (int j = 0; j < 8; ++j) { o0[j] = t[c + j][row]; o1[j] = t[c + 8 + j][row]; }
    const int a_   = c >> 4;
    const int base = (a_ >> 1) * 32 + (a_ & 1) * 4;
    us4 g0, g1, g2, g3;
#pragma unroll
    for (int i = 0; i < 4; ++i) { g0[i] = o0[i]; g1[i] = o0[4 + i]; g2[i] = o1[i]; g3[i] = o1[4 + i]; }
    unsigned short* dst = out + (size_t)(gc + row) * SEQ + gr + base;
    *(us4*)dst        = g0;
    *(us4*)(dst + 8)  = g1;
    *(us4*)(dst + 16) = g2;
    *(us4*)(dst + 24) = g3;
}

// ---------------- fused QKV projection GEMM, 128x128 tile ----------------
__global__ __launch_bounds__(256) void qkv_gemm(
    const unsigned short* __restrict__ X,
    const unsigned short* __restrict__ Wq, const unsigned short* __restrict__ Wk,
    const unsigned short* __restrict__ Wv,
    const float* __restrict__ bq, const float* __restrict__ bk, const float* __restrict__ bv,
    unsigned short* __restrict__ Qo, unsigned short* __restrict__ Ko, unsigned short* __restrict__ Vo)
{
    __shared__ unsigned short As[128 * 64];
    __shared__ unsigned short Bs[128 * 64];

    const int region = blockIdx.y >> 3;
    const unsigned short* W   = region == 0 ? Wq : (region == 1 ? Wk : Wv);
    const float*         bias = region == 0 ? bq : (region == 1 ? bk : bv);
    unsigned short*      out  = region == 0 ? Qo : (region == 1 ? Ko : Vo);
    const float scale = region == 0 ? 0.18033688011112042f : 1.0f;   // 0.125 * log2(e)

    const int tid  = threadIdx.x;
    const int wave = tid >> 6;
    const int lane = tid & 63;
    const int quad = lane >> 4;
    const int l16  = lane & 15;
    const int wm   = (wave >> 1) * 64;
    const int wn   = (wave & 1) * 64;
    const int bm   = blockIdx.x * 128;
    const int bn   = (blockIdx.y & 7) * 128;

    f4 acc[4][4];
#pragma unroll
    for (int a = 0; a < 4; ++a)
#pragma unroll
        for (int b = 0; b < 4; ++b) acc[a][b] = (f4){0, 0, 0, 0};

    const int rsub = lane >> 3;
    const int gc   = ((lane & 7) ^ rsub) * 8;
    const int swz  = l16 & 7;

    for (int k0 = 0; k0 < EMB; k0 += 64) {
        __syncthreads();
#pragma unroll
        for (int i = 0; i < 4; ++i) {
            const int cb = i * 4 + wave;
            const int r  = cb * 8 + rsub;
            gl2lds16(X + (size_t)(bm + r) * EMB + k0 + gc, &As[cb * 512]);
            gl2lds16(W + (size_t)(bn + r) * EMB + k0 + gc, &Bs[cb * 512]);
        }
        __syncthreads();
#pragma unroll
        for (int kc = 0; kc < 2; ++kc) {
            s8 af[4], bf[4];
#pragma unroll
            for (int t = 0; t < 4; ++t) {
                const int seg = (kc * 4 + quad) ^ swz;
                af[t] = *(const s8*)&As[(wm + t * 16 + l16) * 64 + seg * 8];
                bf[t] = *(const s8*)&Bs[(wn + t * 16 + l16) * 64 + seg * 8];
            }
#pragma unroll
            for (int tm = 0; tm < 4; ++tm)
#pragma unroll
                for (int tn = 0; tn < 4; ++tn)
                    acc[tm][tn] = __builtin_amdgcn_mfma_f32_16x16x32_bf16(af[tm], bf[tn], acc[tm][tn], 0, 0, 0);
        }
    }

#pragma unroll
    for (int tn = 0; tn < 4; ++tn) {
        const int n = bn + wn + tn * 16 + l16;
        const float bv2 = bias[n];
#pragma unroll
        for (int tm = 0; tm < 4; ++tm)
#pragma unroll
            for (int rr = 0; rr < 4; ++rr) {
                const int m = bm + wm + tm * 16 + quad * 4 + rr;
                out[(size_t)m * EMB + n] = f2bf((acc[tm][tn][rr] + bv2) * scale);
            }
    }
}

// ---------------- output projection GEMM, 128x64 tile, fp32 out ----------------
__global__ __launch_bounds__(256) void gemm_op(
    const unsigned short* __restrict__ A, const unsigned short* __restrict__ B,
    const float* __restrict__ bias, float* __restrict__ C)
{
    __shared__ unsigned short As[128 * 64];
    __shared__ unsigned short Bs[64 * 64];

    const int tid  = threadIdx.x;
    const int wave = tid >> 6;
    const int lane = tid & 63;
    const int quad = lane >> 4;
    const int l16  = lane & 15;
    const int wm   = (wave >> 1) * 64;
    const int wn   = (wave & 1) * 32;
    const int bm   = blockIdx.x * 128;
    const int bn   = blockIdx.y * 64;

    f4 acc[4][2];
#pragma unroll
    for (int a = 0; a < 4; ++a) { acc[a][0] = (f4){0,0,0,0}; acc[a][1] = (f4){0,0,0,0}; }

    const int rsub = lane >> 3;
    const int gc   = ((lane & 7) ^ rsub) * 8;
    const int swz  = l16 & 7;

    for (int k0 = 0; k0 < EMB; k0 += 64) {
        __syncthreads();
#pragma unroll
        for (int i = 0; i < 6; ++i) {
            const int cb = i * 4 + wave;
            if (cb < 16) {
                gl2lds16(A + (size_t)(bm + cb * 8 + rsub) * EMB + k0 + gc, &As[cb * 512]);
            } else {
                const int c2 = cb - 16;
                gl2lds16(B + (size_t)(bn + c2 * 8 + rsub) * EMB + k0 + gc, &Bs[c2 * 512]);
            }
        }
        __syncthreads();
#pragma unroll
        for (int kc = 0; kc < 2; ++kc) {
            const int seg = (kc * 4 + quad) ^ swz;
            s8 af[4], bf[2];
#pragma unroll
            for (int t = 0; t < 4; ++t)
                af[t] = *(const s8*)&As[(wm + t * 16 + l16) * 64 + seg * 8];
#pragma unroll
            for (int t = 0; t < 2; ++t)
                bf[t] = *(const s8*)&Bs[(wn + t * 16 + l16) * 64 + seg * 8];
#pragma unroll
            for (int tm = 0; tm < 4; ++tm)
#pragma unroll
                for (int tn = 0; tn < 2; ++tn)
                    acc[tm][tn] = __builtin_amdgcn_mfma_f32_16x16x32_bf16(af[tm], bf[tn], acc[tm][tn], 0, 0, 0);
        }
    }

#pragma unroll
    for (int tn = 0; tn < 2; ++tn) {
        const int n = bn + wn + tn * 16 + l16;
        const float bv2 = bias[n];
#pragma unroll
        for (int tm = 0; tm < 4; ++tm)
#pragma unroll
            for (int rr = 0; rr < 4; ++rr) {
                const int m = bm + wm + tm * 16 + quad * 4 + rr;
                C[(size_t)m * EMB + n] = acc[tm][tn][rr] + bv2;
            }
    }
}

// ---------------- Flash attention (causal): 32 q per wave, dual-tile, shared staging ----------------
// Q,K: bf16 [SEQ][EMB] (Q pre-scaled 0.125*log2e). Vt: bf16 [EMB][SEQ], k-permuted cols.
// Block = 256 thr / 4 waves. Waves 0,1 -> tile (63-u) [rows (wave&1)*32 .. +31],
// waves 2,3 -> tile u, ONE shared K/V staging stream over j=0..63-u.
// Each wave owns 32 q as TWO 16-row B-frag groups (q_own, q_own+16) -> every K/V LDS
// fragment feeds 2 MFMA (halves LDS read BW per unit work vs 16q/wave).
// Per-block MFMA work = 4x65 units (constant). Grid (NH,32), u = y<16 ? y : 47-y
// pairs (u,31-u) per CU -> 97 staging steps/CU constant.
__global__ __launch_bounds__(256) void attn_kernel(
    const unsigned short* __restrict__ Qg, const unsigned short* __restrict__ Kg,
    const unsigned short* __restrict__ Vtg, unsigned short* __restrict__ Og)
{
    __shared__ unsigned short Ks[2][64][72];
    __shared__ unsigned short Vs[2][64][72];

    const int tid  = threadIdx.x;
    const int wave = tid >> 6;
    const int lane = tid & 63;
    const int quad = lane >> 4;
    const int l16  = lane & 15;
    const int h    = blockIdx.x;
    const int y    = blockIdx.y;
    const int u    = (y < 16) ? y : 47 - y;
    const int jmax = 63 - u;
    const int tileMine = (wave < 2) ? (63 - u) : u;
    const int jmine    = (wave < 2) ? jmax : u;
    const int colbase = h * DK;
    const int wrow0 = tileMine * 64 + (wave & 1) * 32;   // 32 contiguous q rows
    const int q_own = wrow0 + l16;                       // group 0; group 1 = q_own+16

    // Q B-frags for both groups: B[n=q=l16][k=quad*8+j]
    s8 qf[2][2];
#pragma unroll
    for (int g2 = 0; g2 < 2; ++g2) {
        const unsigned short* q = Qg + (size_t)(q_own + 16 * g2) * EMB + colbase + quad * 8;
        qf[g2][0] = *(const s8*)(q);
        qf[g2][1] = *(const s8*)(q + 32);
    }

    // staging: 256 thr, 4 thr/row, 2 us8 per matrix per thread
    const int row = tid >> 2;
    const int c0  = (tid & 3) * 16;
    const unsigned short* kptr = Kg  + (size_t)row * EMB + colbase + c0;
    const unsigned short* vptr = Vtg + (size_t)(colbase + row) * SEQ + c0;   // pre-permuted

    us8 kr0 = *(const us8*)kptr, kr1 = *(const us8*)(kptr + 8);
    us8 vr0 = *(const us8*)vptr, vr1 = *(const us8*)(vptr + 8);
    *(us8*)&Ks[0][row][c0]     = kr0;
    *(us8*)&Ks[0][row][c0 + 8] = kr1;
    *(us8*)&Vs[0][row][c0]     = vr0;
    *(us8*)&Vs[0][row][c0 + 8] = vr1;
    kr0 = *(const us8*)(kptr + (size_t)64 * EMB);
    kr1 = *(const us8*)(kptr + (size_t)64 * EMB + 8);
    vr0 = *(const us8*)(vptr + 64);
    vr1 = *(const us8*)(vptr + 64 + 8);

    float l_i[2] = {0.0f, 0.0f};
    f4 o[2][4];
#pragma unroll
    for (int g2 = 0; g2 < 2; ++g2)
#pragma unroll
        for (int t = 0; t < 4; ++t) o[g2][t] = (f4){0, 0, 0, 0};

    for (int j = 0; j <= jmax; ++j) {
        __syncthreads();
        const int cur = j & 1;
        if (j < jmax) {
            const int nxt = cur ^ 1;
            *(us8*)&Ks[nxt][row][c0]     = kr0;
            *(us8*)&Ks[nxt][row][c0 + 8] = kr1;
            *(us8*)&Vs[nxt][row][c0]     = vr0;
            *(us8*)&Vs[nxt][row][c0 + 8] = vr1;
            if (j + 1 < jmax) {
                const unsigned short* kn = kptr + (size_t)(j + 2) * 64 * EMB;
                const unsigned short* vn = vptr + (j + 2) * 64;
                kr0 = *(const us8*)kn;  kr1 = *(const us8*)(kn + 8);
                vr0 = *(const us8*)vn;  vr1 = *(const us8*)(vn + 8);
            }
        }

        if (j <= jmine) {
            // S^T[k][q] = K . Q^T for both q-groups; each kv frag feeds 2 MFMA
            f4 s[2][4];
#pragma unroll
            for (int g2 = 0; g2 < 2; ++g2)
#pragma unroll
                for (int t = 0; t < 4; ++t) s[g2][t] = (f4){0, 0, 0, 0};
#pragma unroll
            for (int kc = 0; kc < 2; ++kc)
#pragma unroll
                for (int t = 0; t < 4; ++t) {
                    s8 kv = *(const s8*)&Ks[cur][t * 16 + l16][kc * 32 + quad * 8];
                    s[0][t] = __builtin_amdgcn_mfma_f32_16x16x32_bf16(kv, qf[0][kc], s[0][t], 0, 0, 0);
                    s[1][t] = __builtin_amdgcn_mfma_f32_16x16x32_bf16(kv, qf[1][kc], s[1][t], 0, 0, 0);
                }

            if (j == jmine) {            // diagonal 64-block (same for both groups)
#pragma unroll
                for (int t = 0; t < 4; ++t) {
                    const int kb = j * 64 + t * 16 + quad * 4;
#pragma unroll
                    for (int r = 0; r < 4; ++r) {
                        if (kb + r > q_own)      s[0][t][r] = -1e30f;
                        if (kb + r > q_own + 16) s[1][t][r] = -1e30f;
                    }
                }
            }

            // fixed-max softmax in exp2 domain (both groups)
            union { int i[8]; s8 v[2]; } pku[2];
#pragma unroll
            for (int g2 = 0; g2 < 2; ++g2) {
                float rs = 0.0f;
#pragma unroll
                for (int t = 0; t < 4; ++t)
#pragma unroll
                    for (int r = 0; r < 4; ++r) {
                        const float p = __builtin_amdgcn_exp2f(s[g2][t][r]);
                        s[g2][t][r] = p;
                        rs += p;
                    }
                rs += __shfl_xor(rs, 16);
                rs += __shfl_xor(rs, 32);
                l_i[g2] += rs;
#pragma unroll
                for (int t = 0; t < 4; ++t) {
                    pku[g2].i[t * 2]     = pkbf(s[g2][t][1], s[g2][t][0]);
                    pku[g2].i[t * 2 + 1] = pkbf(s[g2][t][3], s[g2][t][2]);
                }
            }

            // O^T[d][q] += V^T . P (both groups; each va frag feeds 2 MFMA)
#pragma unroll
            for (int kc = 0; kc < 2; ++kc)
#pragma unroll
                for (int t = 0; t < 4; ++t) {
                    s8 va = *(const s8*)&Vs[cur][t * 16 + l16][kc * 32 + quad * 8];
                    o[0][t] = __builtin_amdgcn_mfma_f32_16x16x32_bf16(va, pku[0].v[kc], o[0][t], 0, 0, 0);
                    o[1][t] = __builtin_amdgcn_mfma_f32_16x16x32_bf16(va, pku[1].v[kc], o[1][t], 0, 0, 0);
                }
        }
    }

    // epilogue: o[g][t][r] = O^T[d = t*16+quad*4+r][q = q_own+16g]
#pragma unroll
    for (int g2 = 0; g2 < 2; ++g2) {
        const float inv = 1.0f / l_i[g2];
#pragma unroll
        for (int t = 0; t < 4; ++t) {
            us4 ov;
#pragma unroll
            for (int r = 0; r < 4; ++r) ov[r] = f2bf(o[g2][t][r] * inv);
            *(us4*)&Og[(size_t)(q_own + 16 * g2) * EMB + colbase + t * 16 + quad * 4] = ov;
        }
    }
}

extern "C" void kernel_launch(void* const* d_in, const int* in_sizes, int n_in,
                              void* d_out, int out_size, void* d_ws, size_t ws_size,
                              hipStream_t stream) {
    const float* x  = (const float*)d_in[0];
    const float* Wq = (const float*)d_in[1];
    const float* bq = (const float*)d_in[2];
    const float* Wk = (const float*)d_in[3];
    const float* bk = (const float*)d_in[4];
    const float* Wv = (const float*)d_in[5];
    const float* bv = (const float*)d_in[6];
    const float* Wo = (const float*)d_in[7];
    const float* bo = (const float*)d_in[8];
    float* out = (float*)d_out;

    unsigned short* ws = (unsigned short*)d_ws;
    unsigned short* xb  = ws;                          // [4096][1024]
    unsigned short* Wqb = xb  + (size_t)SEQ * EMB;     // [1024][1024] x4
    unsigned short* Wkb = Wqb + (size_t)EMB * EMB;
    unsigned short* Wvb = Wkb + (size_t)EMB * EMB;
    unsigned short* Wob = Wvb + (size_t)EMB * EMB;
    unsigned short* Qb  = Wob + (size_t)EMB * EMB;     // [4096][1024], pre-scaled 0.125*log2e
    unsigned short* Kb  = Qb  + (size_t)SEQ * EMB;     // [4096][1024]
    unsigned short* Vtb = Kb  + (size_t)SEQ * EMB;     // [1024][4096]  V^T, k-permuted cols
    unsigned short* Ab  = Vtb + (size_t)SEQ * EMB;     // V (pre-transpose), then attn out

    cvt_all<<<8192, 256, 0, stream>>>(x, Wq, Wk, Wv, Wo, xb, Wqb, Wkb, Wvb, Wob);

    qkv_gemm<<<dim3(SEQ / 128, 24), 256, 0, stream>>>(xb, Wqb, Wkb, Wvb, bq, bk, bv, Qb, Kb, Ab);

    transpose_kernel<<<dim3(SEQ / 64, EMB / 64), 256, 0, stream>>>(Ab, Vtb);

    attn_kernel<<<dim3(NH, 32), 256, 0, stream>>>(Qb, Kb, Vtb, Ab);

    gemm_op<<<dim3(SEQ / 128, EMB / 64), 256, 0, stream>>>(Ab, Wob, bo, out);
}

// Round 10
// 221.868 us; speedup vs baseline: 1.0246x; 1.0246x over previous
//
#include <hip/hip_runtime.h>
#include <hip/hip_bf16.h>
#include <math.h>

#define SEQ 4096
#define EMB 1024
#define NH  16
#define DK  64

typedef __attribute__((ext_vector_type(8))) unsigned short us8;
typedef __attribute__((ext_vector_type(8))) short         s8;
typedef __attribute__((ext_vector_type(4))) unsigned short us4;
typedef __attribute__((ext_vector_type(4))) float          f4;

static __device__ __forceinline__ unsigned short f2bf(float f) {
    union { float f; unsigned u; } v; v.f = f;
    unsigned r = v.u + 0x7FFF + ((v.u >> 16) & 1);
    return (unsigned short)(r >> 16);
}

__device__ __forceinline__ void gl2lds16(const void* g, void* l) {
    __builtin_amdgcn_global_load_lds((const __attribute__((address_space(1))) void*)g,
                                     (__attribute__((address_space(3))) void*)l, 16, 0, 0);
}

// pack two fp32 -> one dword of two truncated bf16 (hi = a, lo = b): one v_perm_b32
__device__ __forceinline__ int pkbf(float a, float b) {
    return (int)__builtin_amdgcn_perm(__float_as_uint(a), __float_as_uint(b), 0x07060302u);
}

// ---------------- fp32 -> bf16 convert, all 5 tensors in one launch ----------------
__global__ void cvt_all(const float* __restrict__ x,
                        const float* __restrict__ w0, const float* __restrict__ w1,
                        const float* __restrict__ w2, const float* __restrict__ w3,
                        unsigned short* __restrict__ xo,
                        unsigned short* __restrict__ o0, unsigned short* __restrict__ o1,
                        unsigned short* __restrict__ o2, unsigned short* __restrict__ o3) {
    const int idx = blockIdx.x * 256 + threadIdx.x;
    const float* in;
    unsigned short* out;
    int off;
    if (idx < (1 << 20)) { in = x; out = xo; off = idx; }
    else {
        const int t = idx - (1 << 20);
        const int w = t >> 18;
        off = t & ((1 << 18) - 1);
        in  = w == 0 ? w0 : (w == 1 ? w1 : (w == 2 ? w2 : w3));
        out = w == 0 ? o0 : (w == 1 ? o1 : (w == 2 ? o2 : o3));
    }
    const float4 v = ((const float4*)in)[off];
    us4 o;
    o[0] = f2bf(v.x); o[1] = f2bf(v.y); o[2] = f2bf(v.z); o[3] = f2bf(v.w);
    ((us4*)out)[off] = o;
}

// ---------------- bf16 64x64 transpose with k-permuted output columns ----------------
// pos(k): k=a*16+b*4+c -> (a>>1)*32 + b*8 + (a&1)*4 + c  (matches attn PV frag layout)
__global__ __launch_bounds__(256) void transpose_kernel(
    const unsigned short* __restrict__ in, unsigned short* __restrict__ out) {
    __shared__ unsigned short t[64][72];
    const int tid = threadIdx.x;
    const int row = tid >> 2, c = (tid & 3) * 16;
    const int gr = blockIdx.x * 64, gc = blockIdx.y * 64;
    const unsigned short* src = in + (size_t)(gr + row) * EMB + gc + c;
    *(us8*)&t[row][c]     = *(const us8*)src;
    *(us8*)&t[row][c + 8] = *(const us8*)(src + 8);
    __syncthreads();
    us8 o0, o1;
#pragma unroll
    for (int j = 0; j < 8; ++j) { o0[j] = t[c + j][row]; o1[j] = t[c + 8 + j][row]; }
    const int a_   = c >> 4;
    const int base = (a_ >> 1) * 32 + (a_ & 1) * 4;
    us4 g0, g1, g2, g3;
#pragma unroll
    for (int i = 0; i < 4; ++i) { g0[i] = o0[i]; g1[i] = o0[4 + i]; g2[i] = o1[i]; g3[i] = o1[4 + i]; }
    unsigned short* dst = out + (size_t)(gc + row) * SEQ + gr + base;
    *(us4*)dst        = g0;
    *(us4*)(dst + 8)  = g1;
    *(us4*)(dst + 16) = g2;
    *(us4*)(dst + 24) = g3;
}

// ---------------- fused QKV projection GEMM, 128x128 tile ----------------
__global__ __launch_bounds__(256) void qkv_gemm(
    const unsigned short* __restrict__ X,
    const unsigned short* __restrict__ Wq, const unsigned short* __restrict__ Wk,
    const unsigned short* __restrict__ Wv,
    const float* __restrict__ bq, const float* __restrict__ bk, const float* __restrict__ bv,
    unsigned short* __restrict__ Qo, unsigned short* __restrict__ Ko, unsigned short* __restrict__ Vo)
{
    __shared__ unsigned short As[128 * 64];
    __shared__ unsigned short Bs[128 * 64];

    const int region = blockIdx.y >> 3;
    const unsigned short* W   = region == 0 ? Wq : (region == 1 ? Wk : Wv);
    const float*         bias = region == 0 ? bq : (region == 1 ? bk : bv);
    unsigned short*      out  = region == 0 ? Qo : (region == 1 ? Ko : Vo);
    const float scale = region == 0 ? 0.18033688011112042f : 1.0f;   // 0.125 * log2(e)

    const int tid  = threadIdx.x;
    const int wave = tid >> 6;
    const int lane = tid & 63;
    const int quad = lane >> 4;
    const int l16  = lane & 15;
    const int wm   = (wave >> 1) * 64;
    const int wn   = (wave & 1) * 64;
    const int bm   = blockIdx.x * 128;
    const int bn   = (blockIdx.y & 7) * 128;

    f4 acc[4][4];
#pragma unroll
    for (int a = 0; a < 4; ++a)
#pragma unroll
        for (int b = 0; b < 4; ++b) acc[a][b] = (f4){0, 0, 0, 0};

    const int rsub = lane >> 3;
    const int gc   = ((lane & 7) ^ rsub) * 8;
    const int swz  = l16 & 7;

    for (int k0 = 0; k0 < EMB; k0 += 64) {
        __syncthreads();
#pragma unroll
        for (int i = 0; i < 4; ++i) {
            const int cb = i * 4 + wave;
            const int r  = cb * 8 + rsub;
            gl2lds16(X + (size_t)(bm + r) * EMB + k0 + gc, &As[cb * 512]);
            gl2lds16(W + (size_t)(bn + r) * EMB + k0 + gc, &Bs[cb * 512]);
        }
        __syncthreads();
#pragma unroll
        for (int kc = 0; kc < 2; ++kc) {
            s8 af[4], bf[4];
#pragma unroll
            for (int t = 0; t < 4; ++t) {
                const int seg = (kc * 4 + quad) ^ swz;
                af[t] = *(const s8*)&As[(wm + t * 16 + l16) * 64 + seg * 8];
                bf[t] = *(const s8*)&Bs[(wn + t * 16 + l16) * 64 + seg * 8];
            }
#pragma unroll
            for (int tm = 0; tm < 4; ++tm)
#pragma unroll
                for (int tn = 0; tn < 4; ++tn)
                    acc[tm][tn] = __builtin_amdgcn_mfma_f32_16x16x32_bf16(af[tm], bf[tn], acc[tm][tn], 0, 0, 0);
        }
    }

#pragma unroll
    for (int tn = 0; tn < 4; ++tn) {
        const int n = bn + wn + tn * 16 + l16;
        const float bv2 = bias[n];
#pragma unroll
        for (int tm = 0; tm < 4; ++tm)
#pragma unroll
            for (int rr = 0; rr < 4; ++rr) {
                const int m = bm + wm + tm * 16 + quad * 4 + rr;
                out[(size_t)m * EMB + n] = f2bf((acc[tm][tn][rr] + bv2) * scale);
            }
    }
}

// ---------------- output projection GEMM, 128x64 tile, fp32 out ----------------
__global__ __launch_bounds__(256) void gemm_op(
    const unsigned short* __restrict__ A, const unsigned short* __restrict__ B,
    const float* __restrict__ bias, float* __restrict__ C)
{
    __shared__ unsigned short As[128 * 64];
    __shared__ unsigned short Bs[64 * 64];

    const int tid  = threadIdx.x;
    const int wave = tid >> 6;
    const int lane = tid & 63;
    const int quad = lane >> 4;
    const int l16  = lane & 15;
    const int wm   = (wave >> 1) * 64;
    const int wn   = (wave & 1) * 32;
    const int bm   = blockIdx.x * 128;
    const int bn   = blockIdx.y * 64;

    f4 acc[4][2];
#pragma unroll
    for (int a = 0; a < 4; ++a) { acc[a][0] = (f4){0,0,0,0}; acc[a][1] = (f4){0,0,0,0}; }

    const int rsub = lane >> 3;
    const int gc   = ((lane & 7) ^ rsub) * 8;
    const int swz  = l16 & 7;

    for (int k0 = 0; k0 < EMB; k0 += 64) {
        __syncthreads();
#pragma unroll
        for (int i = 0; i < 6; ++i) {
            const int cb = i * 4 + wave;
            if (cb < 16) {
                gl2lds16(A + (size_t)(bm + cb * 8 + rsub) * EMB + k0 + gc, &As[cb * 512]);
            } else {
                const int c2 = cb - 16;
                gl2lds16(B + (size_t)(bn + c2 * 8 + rsub) * EMB + k0 + gc, &Bs[c2 * 512]);
            }
        }
        __syncthreads();
#pragma unroll
        for (int kc = 0; kc < 2; ++kc) {
            const int seg = (kc * 4 + quad) ^ swz;
            s8 af[4], bf[2];
#pragma unroll
            for (int t = 0; t < 4; ++t)
                af[t] = *(const s8*)&As[(wm + t * 16 + l16) * 64 + seg * 8];
#pragma unroll
            for (int t = 0; t < 2; ++t)
                bf[t] = *(const s8*)&Bs[(wn + t * 16 + l16) * 64 + seg * 8];
#pragma unroll
            for (int tm = 0; tm < 4; ++tm)
#pragma unroll
                for (int tn = 0; tn < 2; ++tn)
                    acc[tm][tn] = __builtin_amdgcn_mfma_f32_16x16x32_bf16(af[tm], bf[tn], acc[tm][tn], 0, 0, 0);
        }
    }

#pragma unroll
    for (int tn = 0; tn < 2; ++tn) {
        const int n = bn + wn + tn * 16 + l16;
        const float bv2 = bias[n];
#pragma unroll
        for (int tm = 0; tm < 4; ++tm)
#pragma unroll
            for (int rr = 0; rr < 4; ++rr) {
                const int m = bm + wm + tm * 16 + quad * 4 + rr;
                C[(size_t)m * EMB + n] = acc[tm][tn][rr] + bv2;
            }
    }
}

// ---------------- Flash attention (causal): 32 q/wave + j-parity split-K ----------------
// Q,K: bf16 [SEQ][EMB] (Q pre-scaled 0.125*log2e). Vt: bf16 [EMB][SEQ], k-permuted cols.
// Block = 512 thr / 8 waves. Wave -> {tile, q-half, j-parity}:
//   waves 0-3: tile A=63-u (halves 0,1 x parity 0,1); waves 4-7: tile B=u likewise.
// Each wave owns 32 q (two 16-row B-frag groups) and processes only j with
// j%2==parity, j<=tile. Fixed-max softmax => partial (o,l) over disjoint j-sets
// merge by ADDITION at the end (LDS, lane-major). 4096 waves total (16/CU) with
// the 1-read:2-MFMA LDS ratio. Shared staging stream j=0..63-u; grid (NH,32),
// u = y<16 ? y : 47-y pairs (u,31-u) per CU.
__global__ __launch_bounds__(512) void attn_kernel(
    const unsigned short* __restrict__ Qg, const unsigned short* __restrict__ Kg,
    const unsigned short* __restrict__ Vtg, unsigned short* __restrict__ Og)
{
    __shared__ unsigned short Ks[2][64][72];
    __shared__ unsigned short Vs[2][64][72];
    __shared__ float Om[4][34][64];           // merge: [pair][32 o + 2 l][lane]

    const int tid  = threadIdx.x;
    const int wave = tid >> 6;
    const int lane = tid & 63;
    const int quad = lane >> 4;
    const int l16  = lane & 15;
    const int h    = blockIdx.x;
    const int y    = blockIdx.y;
    const int u    = (y < 16) ? y : 47 - y;
    const int jmax = 63 - u;
    const int myTile = (wave < 4) ? (63 - u) : u;
    const int parity = (wave >> 1) & 1;
    const int half   = wave & 1;
    const int colbase = h * DK;
    const int wrow0 = myTile * 64 + half * 32;
    const int q_own = wrow0 + l16;                 // group 0; group 1 = q_own+16

    // Q B-frags for both groups: B[n=q=l16][k=quad*8+j]
    s8 qf[2][2];
#pragma unroll
    for (int g2 = 0; g2 < 2; ++g2) {
        const unsigned short* q = Qg + (size_t)(q_own + 16 * g2) * EMB + colbase + quad * 8;
        qf[g2][0] = *(const s8*)(q);
        qf[g2][1] = *(const s8*)(q + 32);
    }

    // staging: 512 thr, 8 thr/row, 1 us8 per matrix per thread
    const int row = tid >> 3;
    const int c0  = (tid & 7) * 8;
    const unsigned short* kptr = Kg  + (size_t)row * EMB + colbase + c0;
    const unsigned short* vptr = Vtg + (size_t)(colbase + row) * SEQ + c0;   // pre-permuted

    us8 kr = *(const us8*)kptr;
    us8 vr = *(const us8*)vptr;
    *(us8*)&Ks[0][row][c0] = kr;
    *(us8*)&Vs[0][row][c0] = vr;
    kr = *(const us8*)(kptr + (size_t)64 * EMB);
    vr = *(const us8*)(vptr + 64);

    float l_i[2] = {0.0f, 0.0f};
    f4 o[2][4];
#pragma unroll
    for (int g2 = 0; g2 < 2; ++g2)
#pragma unroll
        for (int t = 0; t < 4; ++t) o[g2][t] = (f4){0, 0, 0, 0};

    for (int j = 0; j <= jmax; ++j) {
        __syncthreads();
        const int cur = j & 1;
        if (j < jmax) {
            const int nxt = cur ^ 1;
            *(us8*)&Ks[nxt][row][c0] = kr;
            *(us8*)&Vs[nxt][row][c0] = vr;
            if (j + 1 < jmax) {
                kr = *(const us8*)(kptr + (size_t)(j + 2) * 64 * EMB);
                vr = *(const us8*)(vptr + (j + 2) * 64);
            }
        }

        if ((j & 1) == parity && j <= myTile) {
            // S^T[k][q] = K . Q^T for both q-groups; each kv frag feeds 2 MFMA
            f4 s[2][4];
#pragma unroll
            for (int g2 = 0; g2 < 2; ++g2)
#pragma unroll
                for (int t = 0; t < 4; ++t) s[g2][t] = (f4){0, 0, 0, 0};
#pragma unroll
            for (int kc = 0; kc < 2; ++kc)
#pragma unroll
                for (int t = 0; t < 4; ++t) {
                    s8 kv = *(const s8*)&Ks[cur][t * 16 + l16][kc * 32 + quad * 8];
                    s[0][t] = __builtin_amdgcn_mfma_f32_16x16x32_bf16(kv, qf[0][kc], s[0][t], 0, 0, 0);
                    s[1][t] = __builtin_amdgcn_mfma_f32_16x16x32_bf16(kv, qf[1][kc], s[1][t], 0, 0, 0);
                }

            if (j == myTile) {           // diagonal 64-block (only the matching-parity wave)
#pragma unroll
                for (int t = 0; t < 4; ++t) {
                    const int kb = j * 64 + t * 16 + quad * 4;
#pragma unroll
                    for (int r = 0; r < 4; ++r) {
                        if (kb + r > q_own)      s[0][t][r] = -1e30f;
                        if (kb + r > q_own + 16) s[1][t][r] = -1e30f;
                    }
                }
            }

            // fixed-max softmax in exp2 domain (both groups)
            union { int i[8]; s8 v[2]; } pku[2];
#pragma unroll
            for (int g2 = 0; g2 < 2; ++g2) {
                float rs = 0.0f;
#pragma unroll
                for (int t = 0; t < 4; ++t)
#pragma unroll
                    for (int r = 0; r < 4; ++r) {
                        const float p = __builtin_amdgcn_exp2f(s[g2][t][r]);
                        s[g2][t][r] = p;
                        rs += p;
                    }
                rs += __shfl_xor(rs, 16);
                rs += __shfl_xor(rs, 32);
                l_i[g2] += rs;
#pragma unroll
                for (int t = 0; t < 4; ++t) {
                    pku[g2].i[t * 2]     = pkbf(s[g2][t][1], s[g2][t][0]);
                    pku[g2].i[t * 2 + 1] = pkbf(s[g2][t][3], s[g2][t][2]);
                }
            }

            // O^T[d][q] += V^T . P (both groups; each va frag feeds 2 MFMA)
#pragma unroll
            for (int kc = 0; kc < 2; ++kc)
#pragma unroll
                for (int t = 0; t < 4; ++t) {
                    s8 va = *(const s8*)&Vs[cur][t * 16 + l16][kc * 32 + quad * 8];
                    o[0][t] = __builtin_amdgcn_mfma_f32_16x16x32_bf16(va, pku[0].v[kc], o[0][t], 0, 0, 0);
                    o[1][t] = __builtin_amdgcn_mfma_f32_16x16x32_bf16(va, pku[1].v[kc], o[1][t], 0, 0, 0);
                }
        }
    }

    // merge parity partials: (o,l) add across wave pairs (w, w^2)
    const int idx = ((wave >> 2) << 1) | half;     // 0..3, shared within a pair
    __syncthreads();
    if (parity) {
#pragma unroll
        for (int g2 = 0; g2 < 2; ++g2) {
#pragma unroll
            for (int t = 0; t < 4; ++t)
#pragma unroll
                for (int r = 0; r < 4; ++r)
                    Om[idx][g2 * 16 + t * 4 + r][lane] = o[g2][t][r];
            Om[idx][32 + g2][lane] = l_i[g2];
        }
    }
    __syncthreads();
    if (!parity) {
#pragma unroll
        for (int g2 = 0; g2 < 2; ++g2) {
#pragma unroll
            for (int t = 0; t < 4; ++t)
#pragma unroll
                for (int r = 0; r < 4; ++r)
                    o[g2][t][r] += Om[idx][g2 * 16 + t * 4 + r][lane];
            l_i[g2] += Om[idx][32 + g2][lane];
        }
        // epilogue: o[g][t][r] = O^T[d = t*16+quad*4+r][q = q_own+16g]
#pragma unroll
        for (int g2 = 0; g2 < 2; ++g2) {
            const float inv = 1.0f / l_i[g2];
#pragma unroll
            for (int t = 0; t < 4; ++t) {
                us4 ov;
#pragma unroll
                for (int r = 0; r < 4; ++r) ov[r] = f2bf(o[g2][t][r] * inv);
                *(us4*)&Og[(size_t)(q_own + 16 * g2) * EMB + colbase + t * 16 + quad * 4] = ov;
            }
        }
    }
}

extern "C" void kernel_launch(void* const* d_in, const int* in_sizes, int n_in,
                              void* d_out, int out_size, void* d_ws, size_t ws_size,
                              hipStream_t stream) {
    const float* x  = (const float*)d_in[0];
    const float* Wq = (const float*)d_in[1];
    const float* bq = (const float*)d_in[2];
    const float* Wk = (const float*)d_in[3];
    const float* bk = (const float*)d_in[4];
    const float* Wv = (const float*)d_in[5];
    const float* bv = (const float*)d_in[6];
    const float* Wo = (const float*)d_in[7];
    const float* bo = (const float*)d_in[8];
    float* out = (float*)d_out;

    unsigned short* ws = (unsigned short*)d_ws;
    unsigned short* xb  = ws;                          // [4096][1024]
    unsigned short* Wqb = xb  + (size_t)SEQ * EMB;     // [1024][1024] x4
    unsigned short* Wkb = Wqb + (size_t)EMB * EMB;
    unsigned short* Wvb = Wkb + (size_t)EMB * EMB;
    unsigned short* Wob = Wvb + (size_t)EMB * EMB;
    unsigned short* Qb  = Wob + (size_t)EMB * EMB;     // [4096][1024], pre-scaled 0.125*log2e
    unsigned short* Kb  = Qb  + (size_t)SEQ * EMB;     // [4096][1024]
    unsigned short* Vtb = Kb  + (size_t)SEQ * EMB;     // [1024][4096]  V^T, k-permuted cols
    unsigned short* Ab  = Vtb + (size_t)SEQ * EMB;     // V (pre-transpose), then attn out

    cvt_all<<<8192, 256, 0, stream>>>(x, Wq, Wk, Wv, Wo, xb, Wqb, Wkb, Wvb, Wob);

    qkv_gemm<<<dim3(SEQ / 128, 24), 256, 0, stream>>>(xb, Wqb, Wkb, Wvb, bq, bk, bv, Qb, Kb, Ab);

    transpose_kernel<<<dim3(SEQ / 64, EMB / 64), 256, 0, stream>>>(Ab, Vtb);

    attn_kernel<<<dim3(NH, 32), 512, 0, stream>>>(Qb, Kb, Vtb, Ab);

    gemm_op<<<dim3(SEQ / 128, EMB / 64), 256, 0, stream>>>(Ab, Wob, bo, out);
}

// Round 11
// 204.864 us; speedup vs baseline: 1.1097x; 1.0830x over previous
//
#include <hip/hip_runtime.h>
#include <hip/hip_bf16.h>
#include <math.h>

#define SEQ 4096
#define EMB 1024
#define NH  16
#define DK  64

typedef __attribute__((ext_vector_type(8))) unsigned short us8;
typedef __attribute__((ext_vector_type(8))) short         s8;
typedef __attribute__((ext_vector_type(4))) unsigned short us4;
typedef __attribute__((ext_vector_type(4))) float          f4;

static __device__ __forceinline__ unsigned short f2bf(float f) {
    union { float f; unsigned u; } v; v.f = f;
    unsigned r = v.u + 0x7FFF + ((v.u >> 16) & 1);
    return (unsigned short)(r >> 16);
}

__device__ __forceinline__ void gl2lds16(const void* g, void* l) {
    __builtin_amdgcn_global_load_lds((const __attribute__((address_space(1))) void*)g,
                                     (__attribute__((address_space(3))) void*)l, 16, 0, 0);
}

// pack two fp32 -> one dword of two truncated bf16 (hi = a, lo = b): one v_perm_b32
__device__ __forceinline__ int pkbf(float a, float b) {
    return (int)__builtin_amdgcn_perm(__float_as_uint(a), __float_as_uint(b), 0x07060302u);
}

// ---------------- fp32 -> bf16 convert, all 5 tensors in one launch ----------------
__global__ void cvt_all(const float* __restrict__ x,
                        const float* __restrict__ w0, const float* __restrict__ w1,
                        const float* __restrict__ w2, const float* __restrict__ w3,
                        unsigned short* __restrict__ xo,
                        unsigned short* __restrict__ o0, unsigned short* __restrict__ o1,
                        unsigned short* __restrict__ o2, unsigned short* __restrict__ o3) {
    const int idx = blockIdx.x * 256 + threadIdx.x;
    const float* in;
    unsigned short* out;
    int off;
    if (idx < (1 << 20)) { in = x; out = xo; off = idx; }
    else {
        const int t = idx - (1 << 20);
        const int w = t >> 18;
        off = t & ((1 << 18) - 1);
        in  = w == 0 ? w0 : (w == 1 ? w1 : (w == 2 ? w2 : w3));
        out = w == 0 ? o0 : (w == 1 ? o1 : (w == 2 ? o2 : o3));
    }
    const float4 v = ((const float4*)in)[off];
    us4 o;
    o[0] = f2bf(v.x); o[1] = f2bf(v.y); o[2] = f2bf(v.z); o[3] = f2bf(v.w);
    ((us4*)out)[off] = o;
}

// ---------------- bf16 64x64 transpose with k-permuted output columns ----------------
// pos(k): k=a*16+b*4+c -> (a>>1)*32 + b*8 + (a&1)*4 + c  (matches attn PV frag layout)
__global__ __launch_bounds__(256) void transpose_kernel(
    const unsigned short* __restrict__ in, unsigned short* __restrict__ out) {
    __shared__ unsigned short t[64][72];
    const int tid = threadIdx.x;
    const int row = tid >> 2, c = (tid & 3) * 16;
    const int gr = blockIdx.x * 64, gc = blockIdx.y * 64;
    const unsigned short* src = in + (size_t)(gr + row) * EMB + gc + c;
    *(us8*)&t[row][c]     = *(const us8*)src;
    *(us8*)&t[row][c + 8] = *(const us8*)(src + 8);
    __syncthreads();
    us8 o0, o1;
#pragma unroll
    for (int j = 0; j < 8; ++j) { o0[j] = t[c + j][row]; o1[j] = t[c + 8 + j][row]; }
    const int a_   = c >> 4;
    const int base = (a_ >> 1) * 32 + (a_ & 1) * 4;
    us4 g0, g1, g2, g3;
#pragma unroll
    for (int i = 0; i < 4; ++i) { g0[i] = o0[i]; g1[i] = o0[4 + i]; g2[i] = o1[i]; g3[i] = o1[4 + i]; }
    unsigned short* dst = out + (size_t)(gc + row) * SEQ + gr + base;
    *(us4*)dst        = g0;
    *(us4*)(dst + 8)  = g1;
    *(us4*)(dst + 16) = g2;
    *(us4*)(dst + 24) = g3;
}

// ---------------- fused QKV projection GEMM, 128x128 tile ----------------
__global__ __launch_bounds__(256) void qkv_gemm(
    const unsigned short* __restrict__ X,
    const unsigned short* __restrict__ Wq, const unsigned short* __restrict__ Wk,
    const unsigned short* __restrict__ Wv,
    const float* __restrict__ bq, const float* __restrict__ bk, const float* __restrict__ bv,
    unsigned short* __restrict__ Qo, unsigned short* __restrict__ Ko, unsigned short* __restrict__ Vo)
{
    __shared__ unsigned short As[128 * 64];
    __shared__ unsigned short Bs[128 * 64];

    const int region = blockIdx.y >> 3;
    const unsigned short* W   = region == 0 ? Wq : (region == 1 ? Wk : Wv);
    const float*         bias = region == 0 ? bq : (region == 1 ? bk : bv);
    unsigned short*      out  = region == 0 ? Qo : (region == 1 ? Ko : Vo);
    const float scale = region == 0 ? 0.18033688011112042f : 1.0f;   // 0.125 * log2(e)

    const int tid  = threadIdx.x;
    const int wave = tid >> 6;
    const int lane = tid & 63;
    const int quad = lane >> 4;
    const int l16  = lane & 15;
    const int wm   = (wave >> 1) * 64;
    const int wn   = (wave & 1) * 64;
    const int bm   = blockIdx.x * 128;
    const int bn   = (blockIdx.y & 7) * 128;

    f4 acc[4][4];
#pragma unroll
    for (int a = 0; a < 4; ++a)
#pragma unroll
        for (int b = 0; b < 4; ++b) acc[a][b] = (f4){0, 0, 0, 0};

    const int rsub = lane >> 3;
    const int gc   = ((lane & 7) ^ rsub) * 8;
    const int swz  = l16 & 7;

    for (int k0 = 0; k0 < EMB; k0 += 64) {
        __syncthreads();
#pragma unroll
        for (int i = 0; i < 4; ++i) {
            const int cb = i * 4 + wave;
            const int r  = cb * 8 + rsub;
            gl2lds16(X + (size_t)(bm + r) * EMB + k0 + gc, &As[cb * 512]);
            gl2lds16(W + (size_t)(bn + r) * EMB + k0 + gc, &Bs[cb * 512]);
        }
        __syncthreads();
#pragma unroll
        for (int kc = 0; kc < 2; ++kc) {
            s8 af[4], bf[4];
#pragma unroll
            for (int t = 0; t < 4; ++t) {
                const int seg = (kc * 4 + quad) ^ swz;
                af[t] = *(const s8*)&As[(wm + t * 16 + l16) * 64 + seg * 8];
                bf[t] = *(const s8*)&Bs[(wn + t * 16 + l16) * 64 + seg * 8];
            }
#pragma unroll
            for (int tm = 0; tm < 4; ++tm)
#pragma unroll
                for (int tn = 0; tn < 4; ++tn)
                    acc[tm][tn] = __builtin_amdgcn_mfma_f32_16x16x32_bf16(af[tm], bf[tn], acc[tm][tn], 0, 0, 0);
        }
    }

#pragma unroll
    for (int tn = 0; tn < 4; ++tn) {
        const int n = bn + wn + tn * 16 + l16;
        const float bv2 = bias[n];
#pragma unroll
        for (int tm = 0; tm < 4; ++tm)
#pragma unroll
            for (int rr = 0; rr < 4; ++rr) {
                const int m = bm + wm + tm * 16 + quad * 4 + rr;
                out[(size_t)m * EMB + n] = f2bf((acc[tm][tn][rr] + bv2) * scale);
            }
    }
}

// ---------------- output projection GEMM, 128x64 tile, fp32 out ----------------
__global__ __launch_bounds__(256) void gemm_op(
    const unsigned short* __restrict__ A, const unsigned short* __restrict__ B,
    const float* __restrict__ bias, float* __restrict__ C)
{
    __shared__ unsigned short As[128 * 64];
    __shared__ unsigned short Bs[64 * 64];

    const int tid  = threadIdx.x;
    const int wave = tid >> 6;
    const int lane = tid & 63;
    const int quad = lane >> 4;
    const int l16  = lane & 15;
    const int wm   = (wave >> 1) * 64;
    const int wn   = (wave & 1) * 32;
    const int bm   = blockIdx.x * 128;
    const int bn   = blockIdx.y * 64;

    f4 acc[4][2];
#pragma unroll
    for (int a = 0; a < 4; ++a) { acc[a][0] = (f4){0,0,0,0}; acc[a][1] = (f4){0,0,0,0}; }

    const int rsub = lane >> 3;
    const int gc   = ((lane & 7) ^ rsub) * 8;
    const int swz  = l16 & 7;

    for (int k0 = 0; k0 < EMB; k0 += 64) {
        __syncthreads();
#pragma unroll
        for (int i = 0; i < 6; ++i) {
            const int cb = i * 4 + wave;
            if (cb < 16) {
                gl2lds16(A + (size_t)(bm + cb * 8 + rsub) * EMB + k0 + gc, &As[cb * 512]);
            } else {
                const int c2 = cb - 16;
                gl2lds16(B + (size_t)(bn + c2 * 8 + rsub) * EMB + k0 + gc, &Bs[c2 * 512]);
            }
        }
        __syncthreads();
#pragma unroll
        for (int kc = 0; kc < 2; ++kc) {
            const int seg = (kc * 4 + quad) ^ swz;
            s8 af[4], bf[2];
#pragma unroll
            for (int t = 0; t < 4; ++t)
                af[t] = *(const s8*)&As[(wm + t * 16 + l16) * 64 + seg * 8];
#pragma unroll
            for (int t = 0; t < 2; ++t)
                bf[t] = *(const s8*)&Bs[(wn + t * 16 + l16) * 64 + seg * 8];
#pragma unroll
            for (int tm = 0; tm < 4; ++tm)
#pragma unroll
                for (int tn = 0; tn < 2; ++tn)
                    acc[tm][tn] = __builtin_amdgcn_mfma_f32_16x16x32_bf16(af[tm], bf[tn], acc[tm][tn], 0, 0, 0);
        }
    }

#pragma unroll
    for (int tn = 0; tn < 2; ++tn) {
        const int n = bn + wn + tn * 16 + l16;
        const float bv2 = bias[n];
#pragma unroll
        for (int tm = 0; tm < 4; ++tm)
#pragma unroll
            for (int rr = 0; rr < 4; ++rr) {
                const int m = bm + wm + tm * 16 + quad * 4 + rr;
                C[(size_t)m * EMB + n] = acc[tm][tn][rr] + bv2;
            }
    }
}

// ---------------- Flash attention (causal): R8 dual-tile + BK=128 j-pairs ----------------
// Q,K: bf16 [SEQ][EMB] (Q pre-scaled 0.125*log2e). Vt: bf16 [EMB][SEQ], k-permuted cols.
// Block = 512 thr / 8 waves: waves 0-3 -> tile A=63-u, waves 4-7 -> tile B=u, one shared
// K/V staging stream. BK=128: each barrier iteration stages TWO 64-row j-tiles
// (buffer rows [0,64) = even j, [64,128) = odd j) -> barrier count halved vs R8, and the
// two sub-tiles give ILP across the softmax chain. u in [0,31] => jmax=63-u >= 32, so the
// odd sub exists except possibly at the final pair (guarded). Grid (NH,32),
// u = y<16 ? y : 47-y pairs (u,31-u) per CU. Fixed-max softmax, exp2 domain, zero-shfl PV.
__global__ __launch_bounds__(512) void attn_kernel(
    const unsigned short* __restrict__ Qg, const unsigned short* __restrict__ Kg,
    const unsigned short* __restrict__ Vtg, unsigned short* __restrict__ Og)
{
    __shared__ unsigned short Ks[2][128][72];
    __shared__ unsigned short Vs[2][128][72];

    const int tid  = threadIdx.x;
    const int wave = tid >> 6;
    const int lane = tid & 63;
    const int quad = lane >> 4;
    const int l16  = lane & 15;
    const int h    = blockIdx.x;
    const int y    = blockIdx.y;
    const int u    = (y < 16) ? y : 47 - y;
    const int jmax = 63 - u;                        // >= 32
    const int jmine = (wave < 4) ? jmax : u;        // this wave's diagonal j
    const int tileMine = (wave < 4) ? (63 - u) : u;
    const int colbase = h * DK;
    const int wrow0 = tileMine * 64 + (wave & 3) * 16;
    const int q_own = wrow0 + l16;

    // Q B-frag from global: B[n=q=l16][k=quad*8+j]
    s8 qf[2];
    {
        const unsigned short* q = Qg + (size_t)q_own * EMB + colbase + quad * 8;
        qf[0] = *(const s8*)(q);
        qf[1] = *(const s8*)(q + 32);
    }

    // staging: 512 thr, 8 thr/row, 1 us8 per matrix per 64-row sub-tile
    const int row = tid >> 3;
    const int c0  = (tid & 7) * 8;
    const unsigned short* kptr = Kg  + (size_t)row * EMB + colbase + c0;
    const unsigned short* vptr = Vtg + (size_t)(colbase + row) * SEQ + c0;   // pre-permuted

    const int imax = jmax >> 1;                     // pair index range 0..imax

    // stage pair 0 (j=0,1; j=1 always exists since jmax>=32)
    {
        us8 a = *(const us8*)kptr;
        us8 b = *(const us8*)(kptr + (size_t)64 * EMB);
        us8 c = *(const us8*)vptr;
        us8 d = *(const us8*)(vptr + 64);
        *(us8*)&Ks[0][row][c0]      = a;
        *(us8*)&Ks[0][64 + row][c0] = b;
        *(us8*)&Vs[0][row][c0]      = c;
        *(us8*)&Vs[0][64 + row][c0] = d;
    }
    // prefetch pair 1 (j=2,3; both exist since jmax>=32)
    us8 kre = *(const us8*)(kptr + (size_t)2 * 64 * EMB);
    us8 kro = *(const us8*)(kptr + (size_t)3 * 64 * EMB);
    us8 vre = *(const us8*)(vptr + 2 * 64);
    us8 vro = *(const us8*)(vptr + 3 * 64);

    float l_i = 0.0f;
    f4 o[4];
#pragma unroll
    for (int t = 0; t < 4; ++t) o[t] = (f4){0, 0, 0, 0};

    for (int i = 0; i <= imax; ++i) {
        __syncthreads();
        const int cur = i & 1;
        if (i < imax) {
            const int nxt = cur ^ 1;
            *(us8*)&Ks[nxt][row][c0]      = kre;
            *(us8*)&Ks[nxt][64 + row][c0] = kro;   // stale if 2(i+1)+1 > jmax: never read
            *(us8*)&Vs[nxt][row][c0]      = vre;
            *(us8*)&Vs[nxt][64 + row][c0] = vro;
            if (i + 1 < imax) {
                const int je = 2 * (i + 2);        // <= jmax guaranteed (i+2 <= imax)
                kre = *(const us8*)(kptr + (size_t)je * 64 * EMB);
                vre = *(const us8*)(vptr + je * 64);
                const int jo = je + 1;
                if (jo <= jmax) {                  // block-uniform guard
                    kro = *(const us8*)(kptr + (size_t)jo * 64 * EMB);
                    vro = *(const us8*)(vptr + jo * 64);
                }
            }
        }

#pragma unroll
        for (int sub = 0; sub < 2; ++sub) {
            const int j = 2 * i + sub;
            if (j <= jmine) {
                const int rb = sub * 64;
                // S^T[k][q] = K . Q^T
                f4 s[4] = { {0,0,0,0}, {0,0,0,0}, {0,0,0,0}, {0,0,0,0} };
#pragma unroll
                for (int kc = 0; kc < 2; ++kc)
#pragma unroll
                    for (int t = 0; t < 4; ++t) {
                        s8 kv = *(const s8*)&Ks[cur][rb + t * 16 + l16][kc * 32 + quad * 8];
                        s[t] = __builtin_amdgcn_mfma_f32_16x16x32_bf16(kv, qf[kc], s[t], 0, 0, 0);
                    }

                if (j == jmine) {                  // diagonal tile: mask k > q
#pragma unroll
                    for (int t = 0; t < 4; ++t) {
                        const int kb = j * 64 + t * 16 + quad * 4;
#pragma unroll
                        for (int r = 0; r < 4; ++r)
                            if (kb + r > q_own) s[t][r] = -1e30f;
                    }
                }

                // fixed-max softmax in exp2 domain; column sum in-reg + 2 shfl
                float rs = 0.0f;
#pragma unroll
                for (int t = 0; t < 4; ++t)
#pragma unroll
                    for (int r = 0; r < 4; ++r) {
                        const float p = __builtin_amdgcn_exp2f(s[t][r]);
                        s[t][r] = p;
                        rs += p;
                    }
                rs += __shfl_xor(rs, 16);
                rs += __shfl_xor(rs, 32);
                l_i += rs;

                // pack P pairs (trunc bf16); own regs ARE the PV B-frag (k-permuted)
                union { int i[8]; s8 v[2]; } pku;
#pragma unroll
                for (int t = 0; t < 4; ++t) {
                    pku.i[t * 2]     = pkbf(s[t][1], s[t][0]);
                    pku.i[t * 2 + 1] = pkbf(s[t][3], s[t][2]);
                }

                // O^T[d][q] += V^T . P
#pragma unroll
                for (int kc = 0; kc < 2; ++kc)
#pragma unroll
                    for (int t = 0; t < 4; ++t) {
                        s8 va = *(const s8*)&Vs[cur][rb + t * 16 + l16][kc * 32 + quad * 8];
                        o[t] = __builtin_amdgcn_mfma_f32_16x16x32_bf16(va, pku.v[kc], o[t], 0, 0, 0);
                    }
            }
        }
    }

    // epilogue: o[t][r] = O^T[d = t*16+quad*4+r][q = l16]; lane stores its q row
    const float inv = 1.0f / l_i;
#pragma unroll
    for (int t = 0; t < 4; ++t) {
        us4 ov;
#pragma unroll
        for (int r = 0; r < 4; ++r) ov[r] = f2bf(o[t][r] * inv);
        *(us4*)&Og[(size_t)q_own * EMB + colbase + t * 16 + quad * 4] = ov;
    }
}

extern "C" void kernel_launch(void* const* d_in, const int* in_sizes, int n_in,
                              void* d_out, int out_size, void* d_ws, size_t ws_size,
                              hipStream_t stream) {
    const float* x  = (const float*)d_in[0];
    const float* Wq = (const float*)d_in[1];
    const float* bq = (const float*)d_in[2];
    const float* Wk = (const float*)d_in[3];
    const float* bk = (const float*)d_in[4];
    const float* Wv = (const float*)d_in[5];
    const float* bv = (const float*)d_in[6];
    const float* Wo = (const float*)d_in[7];
    const float* bo = (const float*)d_in[8];
    float* out = (float*)d_out;

    unsigned short* ws = (unsigned short*)d_ws;
    unsigned short* xb  = ws;                          // [4096][1024]
    unsigned short* Wqb = xb  + (size_t)SEQ * EMB;     // [1024][1024] x4
    unsigned short* Wkb = Wqb + (size_t)EMB * EMB;
    unsigned short* Wvb = Wkb + (size_t)EMB * EMB;
    unsigned short* Wob = Wvb + (size_t)EMB * EMB;
    unsigned short* Qb  = Wob + (size_t)EMB * EMB;     // [4096][1024], pre-scaled 0.125*log2e
    unsigned short* Kb  = Qb  + (size_t)SEQ * EMB;     // [4096][1024]
    unsigned short* Vtb = Kb  + (size_t)SEQ * EMB;     // [1024][4096]  V^T, k-permuted cols
    unsigned short* Ab  = Vtb + (size_t)SEQ * EMB;     // V (pre-transpose), then attn out

    cvt_all<<<8192, 256, 0, stream>>>(x, Wq, Wk, Wv, Wo, xb, Wqb, Wkb, Wvb, Wob);

    qkv_gemm<<<dim3(SEQ / 128, 24), 256, 0, stream>>>(xb, Wqb, Wkb, Wvb, bq, bk, bv, Qb, Kb, Ab);

    transpose_kernel<<<dim3(SEQ / 64, EMB / 64), 256, 0, stream>>>(Ab, Vtb);

    attn_kernel<<<dim3(NH, 32), 512, 0, stream>>>(Qb, Kb, Vtb, Ab);

    gemm_op<<<dim3(SEQ / 128, EMB / 64), 256, 0, stream>>>(Ab, Wob, bo, out);
}